// Round 1
// baseline (1209.753 us; speedup 1.0000x reference)
//
#include <hip/hip_runtime.h>

// Sizes
#define B_    64
#define KFC   131072   // 128*32*32
#define O1    256
#define NCLS  1000

// ---------------------------------------------------------------------------
// conv1: x[64,3,128,128] -> y[64,64,64,64]  (3x3 conv pad1 + bias + relu + 2x2 maxpool)
// thread = (b, c, 2x2 pooled block)  => 4x4 conv pixels, 6x6 input window
// ---------------------------------------------------------------------------
__global__ __launch_bounds__(256) void conv1_kernel(
    const float* __restrict__ x, const float* __restrict__ w1,
    const float* __restrict__ b1, float* __restrict__ y) {
  int tid = blockIdx.x * 256 + threadIdx.x;
  int pw2 = tid & 31;
  int ph2 = (tid >> 5) & 31;
  int c   = (tid >> 10) & 63;
  int b   = tid >> 16;

  float wr[3][9];
#pragma unroll
  for (int ci = 0; ci < 3; ++ci)
#pragma unroll
    for (int k = 0; k < 9; ++k)
      wr[ci][k] = w1[c * 27 + ci * 9 + k];

  float acc[4][4];
#pragma unroll
  for (int a = 0; a < 4; ++a)
#pragma unroll
    for (int q = 0; q < 4; ++q) acc[a][q] = 0.f;

  int h0 = ph2 * 4 - 1, w0 = pw2 * 4 - 1;
#pragma unroll
  for (int ci = 0; ci < 3; ++ci) {
    float in6[6][6];
#pragma unroll
    for (int r = 0; r < 6; ++r) {
      int ih = h0 + r;
#pragma unroll
      for (int s = 0; s < 6; ++s) {
        int iw = w0 + s;
        bool ok = ((unsigned)ih < 128u) && ((unsigned)iw < 128u);
        in6[r][s] = ok ? x[(b * 3 + ci) * 16384 + ih * 128 + iw] : 0.f;
      }
    }
#pragma unroll
    for (int a = 0; a < 4; ++a)
#pragma unroll
      for (int q = 0; q < 4; ++q) {
        float s = acc[a][q];
#pragma unroll
        for (int kh = 0; kh < 3; ++kh)
#pragma unroll
          for (int kw = 0; kw < 3; ++kw)
            s += in6[a + kh][q + kw] * wr[ci][kh * 3 + kw];
        acc[a][q] = s;
      }
  }
  float bias = b1[c];
#pragma unroll
  for (int pr = 0; pr < 2; ++pr)
#pragma unroll
    for (int pc = 0; pc < 2; ++pc) {
      float m = fmaxf(fmaxf(acc[2 * pr][2 * pc], acc[2 * pr][2 * pc + 1]),
                      fmaxf(acc[2 * pr + 1][2 * pc], acc[2 * pr + 1][2 * pc + 1]));
      m = fmaxf(m + bias, 0.f);
      int ph = ph2 * 2 + pr, pw = pw2 * 2 + pc;
      y[((b * 64 + c) << 12) + (ph << 6) + pw] = m;
    }
}

// ---------------------------------------------------------------------------
// conv2: y1[64,64,64,64] -> A[64,131072]  (flattened [64,128,32,32])
// block: fixed b, 8-o tile, 16x16 pooled spatial tile (32x32 conv, 34x34 input in LDS)
// thread: 2 o x (2x2 pooled) = 2 o x (4x4 conv)
// ---------------------------------------------------------------------------
__global__ __launch_bounds__(256) void conv2_kernel(
    const float* __restrict__ xin, const float* __restrict__ w2,
    const float* __restrict__ b2, float* __restrict__ A) {
  __shared__ float tile[34][36];
  int t  = threadIdx.x;
  int gb = blockIdx.x;
  int sx = gb & 1, sy = (gb >> 1) & 1, ot = (gb >> 2) & 15, b = gb >> 6;
  int pw2 = t & 7, ph2 = (t >> 3) & 7, o2 = t >> 6;
  int o0  = ot * 8 + o2 * 2;
  int cy0 = sy * 32, cx0 = sx * 32;

  float acc[2][4][4];
#pragma unroll
  for (int oo = 0; oo < 2; ++oo)
#pragma unroll
    for (int a = 0; a < 4; ++a)
#pragma unroll
      for (int q = 0; q < 4; ++q) acc[oo][a][q] = 0.f;

  for (int c = 0; c < 64; ++c) {
    __syncthreads();
    const float* src = xin + (b * 64 + c) * 4096;
    for (int i = t; i < 34 * 36; i += 256) {
      int r = i / 36, s = i - r * 36;
      int ih = cy0 - 1 + r, iw = cx0 - 1 + s;
      bool ok = ((unsigned)ih < 64u) && ((unsigned)iw < 64u);
      tile[r][s] = ok ? src[(ih << 6) + iw] : 0.f;
    }
    __syncthreads();

    float wa[9], wb[9];
#pragma unroll
    for (int k = 0; k < 9; ++k) {
      wa[k] = w2[(o0 + 0) * 576 + c * 9 + k];
      wb[k] = w2[(o0 + 1) * 576 + c * 9 + k];
    }

    float in6[6][6];
    int r0 = ph2 * 4, s0 = pw2 * 4;
#pragma unroll
    for (int r = 0; r < 6; ++r) {
      float4 lo = *(const float4*)&tile[r0 + r][s0];
      float2 hi = *(const float2*)&tile[r0 + r][s0 + 4];
      in6[r][0] = lo.x; in6[r][1] = lo.y; in6[r][2] = lo.z; in6[r][3] = lo.w;
      in6[r][4] = hi.x; in6[r][5] = hi.y;
    }
#pragma unroll
    for (int a = 0; a < 4; ++a)
#pragma unroll
      for (int q = 0; q < 4; ++q) {
        float s0acc = acc[0][a][q], s1acc = acc[1][a][q];
#pragma unroll
        for (int kh = 0; kh < 3; ++kh)
#pragma unroll
          for (int kw = 0; kw < 3; ++kw) {
            float v = in6[a + kh][q + kw];
            s0acc += v * wa[kh * 3 + kw];
            s1acc += v * wb[kh * 3 + kw];
          }
        acc[0][a][q] = s0acc;
        acc[1][a][q] = s1acc;
      }
  }

#pragma unroll
  for (int oo = 0; oo < 2; ++oo) {
    int o = o0 + oo;
    float bias = b2[o];
#pragma unroll
    for (int pr = 0; pr < 2; ++pr)
#pragma unroll
      for (int pc = 0; pc < 2; ++pc) {
        float m = fmaxf(fmaxf(acc[oo][2 * pr][2 * pc], acc[oo][2 * pr][2 * pc + 1]),
                        fmaxf(acc[oo][2 * pr + 1][2 * pc], acc[oo][2 * pr + 1][2 * pc + 1]));
        m = fmaxf(m + bias, 0.f);
        int prow = sy * 16 + ph2 * 2 + pr;
        int pcol = sx * 16 + pw2 * 2 + pc;
        A[(size_t)b * KFC + o * 1024 + prow * 32 + pcol] = m;
      }
  }
}

// ---------------------------------------------------------------------------
// fc1: C[64,256] = A[64,131072] @ W[256,131072]^T  (k-split into 512 chunks of 256)
// block p: full 64x256 partial over k-chunk; thread: 4 o x 16 b accumulators
// ---------------------------------------------------------------------------
__device__ __forceinline__ float getq(float4 v, int q) {
  switch (q) { case 0: return v.x; case 1: return v.y; case 2: return v.z; default: return v.w; }
}

__global__ __launch_bounds__(256) void fc1_kernel(
    const float* __restrict__ A, const float* __restrict__ W,
    float* __restrict__ P) {
  __shared__ float T[64][68];
  int t = threadIdx.x, p = blockIdx.x;
  int kbase = p << 8;
  int l = t & 63, g = t >> 6;

  float acc[4][16];
#pragma unroll
  for (int j = 0; j < 4; ++j)
#pragma unroll
    for (int i = 0; i < 16; ++i) acc[j][i] = 0.f;

  const float* wr0 = W + (size_t)(4 * l + 0) * KFC + kbase;
  const float* wr1 = W + (size_t)(4 * l + 1) * KFC + kbase;
  const float* wr2 = W + (size_t)(4 * l + 2) * KFC + kbase;
  const float* wr3 = W + (size_t)(4 * l + 3) * KFC + kbase;

  int sb = t >> 2, sk = (t & 3) << 4;
  const float* ap = A + (size_t)sb * KFC + kbase + sk;

  for (int kk0 = 0; kk0 < 256; kk0 += 64) {
    __syncthreads();
    float4 v0 = *(const float4*)(ap + kk0);
    float4 v1 = *(const float4*)(ap + kk0 + 4);
    float4 v2 = *(const float4*)(ap + kk0 + 8);
    float4 v3 = *(const float4*)(ap + kk0 + 12);
    T[sk + 0][sb] = v0.x;  T[sk + 1][sb] = v0.y;  T[sk + 2][sb] = v0.z;  T[sk + 3][sb] = v0.w;
    T[sk + 4][sb] = v1.x;  T[sk + 5][sb] = v1.y;  T[sk + 6][sb] = v1.z;  T[sk + 7][sb] = v1.w;
    T[sk + 8][sb] = v2.x;  T[sk + 9][sb] = v2.y;  T[sk + 10][sb] = v2.z; T[sk + 11][sb] = v2.w;
    T[sk + 12][sb] = v3.x; T[sk + 13][sb] = v3.y; T[sk + 14][sb] = v3.z; T[sk + 15][sb] = v3.w;
    __syncthreads();

    for (int kk = 0; kk < 64; kk += 4) {
      float4 wq0 = *(const float4*)(wr0 + kk0 + kk);
      float4 wq1 = *(const float4*)(wr1 + kk0 + kk);
      float4 wq2 = *(const float4*)(wr2 + kk0 + kk);
      float4 wq3 = *(const float4*)(wr3 + kk0 + kk);
#pragma unroll
      for (int q = 0; q < 4; ++q) {
        const float* trow = &T[kk + q][g << 4];
        float4 t0 = *(const float4*)(trow + 0);
        float4 t1 = *(const float4*)(trow + 4);
        float4 t2 = *(const float4*)(trow + 8);
        float4 t3 = *(const float4*)(trow + 12);
        float tv[16] = {t0.x, t0.y, t0.z, t0.w, t1.x, t1.y, t1.z, t1.w,
                        t2.x, t2.y, t2.z, t2.w, t3.x, t3.y, t3.z, t3.w};
        float w0 = getq(wq0, q), w1 = getq(wq1, q), w2v = getq(wq2, q), w3 = getq(wq3, q);
#pragma unroll
        for (int i = 0; i < 16; ++i) {
          acc[0][i] += w0 * tv[i];
          acc[1][i] += w1 * tv[i];
          acc[2][i] += w2v * tv[i];
          acc[3][i] += w3 * tv[i];
        }
      }
    }
  }

  float* dst = P + (size_t)p * 16384 + (l << 2) * 64 + (g << 4);
#pragma unroll
  for (int j = 0; j < 4; ++j)
#pragma unroll
    for (int i4 = 0; i4 < 4; ++i4) {
      float4 v = make_float4(acc[j][i4 * 4 + 0], acc[j][i4 * 4 + 1],
                             acc[j][i4 * 4 + 2], acc[j][i4 * 4 + 3]);
      *(float4*)(dst + j * 64 + i4 * 4) = v;
    }
}

// fc1 partial reduce + bias + relu -> Y[64,256] (stored b-major)
__global__ __launch_bounds__(256) void fc1_reduce_kernel(
    const float* __restrict__ P, const float* __restrict__ b1,
    float* __restrict__ Y) {
  int idx = blockIdx.x * 256 + threadIdx.x;  // o*64 + b
  float s0 = 0, s1 = 0, s2 = 0, s3 = 0;
  for (int p = 0; p < 512; p += 4) {
    s0 += P[(size_t)(p + 0) * 16384 + idx];
    s1 += P[(size_t)(p + 1) * 16384 + idx];
    s2 += P[(size_t)(p + 2) * 16384 + idx];
    s3 += P[(size_t)(p + 3) * 16384 + idx];
  }
  float s = (s0 + s1) + (s2 + s3);
  int o = idx >> 6, b = idx & 63;
  Y[b * 256 + o] = fmaxf(s + b1[o], 0.f);
}

// fc2: out[64,1000] = Y[64,256] @ W2[1000,256]^T + b2
__global__ __launch_bounds__(256) void fc2_kernel(
    const float* __restrict__ Y, const float* __restrict__ W2,
    const float* __restrict__ b2, float* __restrict__ out) {
  int tid = blockIdx.x * 256 + threadIdx.x;
  if (tid >= 64 * NCLS) return;
  int b = tid / NCLS, n = tid - b * NCLS;
  const float4* yv = (const float4*)(Y + b * 256);
  const float4* wv = (const float4*)(W2 + n * 256);
  float acc = 0.f;
#pragma unroll 8
  for (int f = 0; f < 64; ++f) {
    float4 a = yv[f], w = wv[f];
    acc += a.x * w.x + a.y * w.y + a.z * w.z + a.w * w.w;
  }
  out[tid] = acc + b2[n];
}

// ---------------------------------------------------------------------------
extern "C" void kernel_launch(void* const* d_in, const int* in_sizes, int n_in,
                              void* d_out, int out_size, void* d_ws, size_t ws_size,
                              hipStream_t stream) {
  const float* x   = (const float*)d_in[0];
  const float* w1  = (const float*)d_in[1];
  const float* b1  = (const float*)d_in[2];
  const float* w2  = (const float*)d_in[3];
  const float* b2  = (const float*)d_in[4];
  const float* fw1 = (const float*)d_in[5];
  const float* fb1 = (const float*)d_in[6];
  const float* fw2 = (const float*)d_in[7];
  const float* fb2 = (const float*)d_in[8];
  float* out = (float*)d_out;

  float* ws0 = (float*)d_ws;         // conv1 out [16777216] floats; later reused for fc1 partials [8388608]
  float* wsA = ws0 + 16777216;       // conv2 out (flattened activations) [8388608]
  float* wsY = wsA + 8388608;        // fc1 out [16384]

  conv1_kernel<<<16384, 256, 0, stream>>>(x, w1, b1, ws0);
  conv2_kernel<<<4096, 256, 0, stream>>>(ws0, w2, b2, wsA);
  fc1_kernel<<<512, 256, 0, stream>>>(wsA, fw1, ws0);
  fc1_reduce_kernel<<<64, 256, 0, stream>>>(ws0, fb1, wsY);
  fc2_kernel<<<250, 256, 0, stream>>>(wsY, fw2, fb2, out);
}

// Round 2
// 537.757 us; speedup vs baseline: 2.2496x; 2.2496x over previous
//
#include <hip/hip_runtime.h>

typedef __attribute__((ext_vector_type(8))) short short8;
typedef __attribute__((ext_vector_type(4))) float f32x4;

#define KFC   131072   // 128*32*32
#define NCLS  1000

__device__ __forceinline__ unsigned short f2bf(float f) {
  union { float f; unsigned u; } v; v.f = f;
  unsigned r = v.u + 0x7FFFu + ((v.u >> 16) & 1u);   // RNE
  return (unsigned short)(r >> 16);
}

// ---------------------------------------------------------------------------
// conv1: x[64,3,128,128] -> y[64,64,64,64] fp32 (3x3 pad1 + bias + relu + 2x2 pool)
// ---------------------------------------------------------------------------
__global__ __launch_bounds__(256) void conv1_kernel(
    const float* __restrict__ x, const float* __restrict__ w1,
    const float* __restrict__ b1, float* __restrict__ y) {
  int tid = blockIdx.x * 256 + threadIdx.x;
  int pw2 = tid & 31;
  int ph2 = (tid >> 5) & 31;
  int c   = (tid >> 10) & 63;
  int b   = tid >> 16;

  float wr[3][9];
#pragma unroll
  for (int ci = 0; ci < 3; ++ci)
#pragma unroll
    for (int k = 0; k < 9; ++k)
      wr[ci][k] = w1[c * 27 + ci * 9 + k];

  float acc[4][4];
#pragma unroll
  for (int a = 0; a < 4; ++a)
#pragma unroll
    for (int q = 0; q < 4; ++q) acc[a][q] = 0.f;

  int h0 = ph2 * 4 - 1, w0 = pw2 * 4 - 1;
#pragma unroll
  for (int ci = 0; ci < 3; ++ci) {
    float in6[6][6];
#pragma unroll
    for (int r = 0; r < 6; ++r) {
      int ih = h0 + r;
#pragma unroll
      for (int s = 0; s < 6; ++s) {
        int iw = w0 + s;
        bool ok = ((unsigned)ih < 128u) && ((unsigned)iw < 128u);
        in6[r][s] = ok ? x[(b * 3 + ci) * 16384 + ih * 128 + iw] : 0.f;
      }
    }
#pragma unroll
    for (int a = 0; a < 4; ++a)
#pragma unroll
      for (int q = 0; q < 4; ++q) {
        float s = acc[a][q];
#pragma unroll
        for (int kh = 0; kh < 3; ++kh)
#pragma unroll
          for (int kw = 0; kw < 3; ++kw)
            s += in6[a + kh][q + kw] * wr[ci][kh * 3 + kw];
        acc[a][q] = s;
      }
  }
  float bias = b1[c];
#pragma unroll
  for (int pr = 0; pr < 2; ++pr)
#pragma unroll
    for (int pc = 0; pc < 2; ++pc) {
      float m = fmaxf(fmaxf(acc[2 * pr][2 * pc], acc[2 * pr][2 * pc + 1]),
                      fmaxf(acc[2 * pr + 1][2 * pc], acc[2 * pr + 1][2 * pc + 1]));
      m = fmaxf(m + bias, 0.f);
      int ph = ph2 * 2 + pr, pw = pw2 * 2 + pc;
      y[((b * 64 + c) << 12) + (ph << 6) + pw] = m;
    }
}

// ---------------------------------------------------------------------------
// weight reorder for conv2: Bprep[((cg*9+pos)*128 + o)*32 + c] = bf16(w2[o][ (cg*32+c)*9 + pos ])
// ---------------------------------------------------------------------------
__global__ __launch_bounds__(256) void prep_w2(
    const float* __restrict__ w2, short* __restrict__ Bp) {
  int i = blockIdx.x * 256 + threadIdx.x;   // 73728 total
  int c = i & 31, o = (i >> 5) & 127, pp = i >> 12;
  int cg = pp / 9, pos = pp - cg * 9;
  Bp[i] = (short)f2bf(w2[o * 576 + (cg * 32 + c) * 9 + pos]);
}

// ---------------------------------------------------------------------------
// conv2 implicit-GEMM MFMA: y1[64,64,64,64] fp32 -> A[64,131072] bf16 (flattened [128,32,32])
// block: b x (4x4 grid of 16x16 conv tiles). 4 waves; wave = M 64 px x N 128 o.
// K = 2 chunks x (9 pos x 32 ch). LDS: [18*18 spatial][32ch + 8 pad] bf16.
// ---------------------------------------------------------------------------
__global__ __launch_bounds__(256) void conv2_mfma(
    const float* __restrict__ xin, const short* __restrict__ Bp,
    const float* __restrict__ b2, unsigned int* __restrict__ A32) {
  __shared__ short tile[324 * 40];
  const int t = threadIdx.x;
  const int blk = blockIdx.x;
  const int tx = blk & 3, ty = (blk >> 2) & 3, b = blk >> 4;
  const int w = t >> 6, lane = t & 63;
  const int l15 = lane & 15, lg = lane >> 4;

  f32x4 acc[4][8];
#pragma unroll
  for (int m = 0; m < 4; ++m)
#pragma unroll
    for (int n = 0; n < 8; ++n) acc[m][n] = (f32x4){0.f, 0.f, 0.f, 0.f};

  const int ih0 = ty * 16 - 1, iw0 = tx * 16 - 1;

#pragma unroll
  for (int cg = 0; cg < 2; ++cg) {
    __syncthreads();
    // stage 18x18 spatial x 32 channels, fp32 -> bf16, channel-contiguous
    for (int p = t; p < 324; p += 256) {
      int sy = p / 18, sx = p - sy * 18;
      int ih = ih0 + sy, iw = iw0 + sx;
      bool ok = ((unsigned)ih < 64u) && ((unsigned)iw < 64u);
      const float* src = xin + (((size_t)(b * 64 + cg * 32)) << 12) + (ih << 6) + iw;
      unsigned* dst = (unsigned*)&tile[p * 40];
#pragma unroll
      for (int cc = 0; cc < 16; ++cc) {
        float f0 = ok ? src[(2 * cc) << 12] : 0.f;
        float f1 = ok ? src[(2 * cc + 1) << 12] : 0.f;
        dst[cc] = (unsigned)f2bf(f0) | ((unsigned)f2bf(f1) << 16);
      }
    }
    __syncthreads();

    const int py0 = w * 4;
#pragma unroll
    for (int pos = 0; pos < 9; ++pos) {
      const int kh = pos / 3, kw = pos % 3;
      short8 af[4];
#pragma unroll
      for (int m = 0; m < 4; ++m) {
        int sy = py0 + m + kh, sx = l15 + kw;
        af[m] = *(const short8*)&tile[(sy * 18 + sx) * 40 + lg * 8];
      }
#pragma unroll
      for (int n = 0; n < 8; ++n) {
        const short8 bf = *(const short8*)(Bp + ((((cg * 9 + pos) << 7) + n * 16 + l15) << 5) + (lg << 3));
#pragma unroll
        for (int m = 0; m < 4; ++m)
          acc[m][n] = __builtin_amdgcn_mfma_f32_16x16x32_bf16(af[m], bf, acc[m][n], 0, 0, 0);
      }
    }
  }

  // epilogue: bias + relu + 2x2 pool, all in-lane; write packed bf16 pairs
  const size_t bbase = ((size_t)b << 16);   // u32 units: 131072 bf16 / 2
#pragma unroll
  for (int n = 0; n < 8; ++n) {
    const int o = n * 16 + l15;
    const float bias = b2[o];
#pragma unroll
    for (int mp = 0; mp < 2; ++mp) {
      const int prow = ty * 8 + w * 2 + mp;
      float v0 = fmaxf(fmaxf(acc[2 * mp][n][0], acc[2 * mp][n][1]),
                       fmaxf(acc[2 * mp + 1][n][0], acc[2 * mp + 1][n][1]));
      float v1 = fmaxf(fmaxf(acc[2 * mp][n][2], acc[2 * mp][n][3]),
                       fmaxf(acc[2 * mp + 1][n][2], acc[2 * mp + 1][n][3]));
      v0 = fmaxf(v0 + bias, 0.f);
      v1 = fmaxf(v1 + bias, 0.f);
      unsigned pk = (unsigned)f2bf(v0) | ((unsigned)f2bf(v1) << 16);
      A32[bbase + (size_t)o * 512 + prow * 16 + tx * 4 + lg] = pk;
    }
  }
}

// ---------------------------------------------------------------------------
// fc1 MFMA (BW-bound): C[64 b][256 o] partials over K-chunks of 2048.
// grid 256 = 64 kc x 4 nt. Per iter: stage W[64 o][128 k] fp32->bf16 + A[64 b][128 k]
// into LDS (stride 136 = conflict-free), register-double-buffered prefetch.
// ---------------------------------------------------------------------------
__global__ __launch_bounds__(256) void fc1_mfma(
    const unsigned short* __restrict__ A, const float* __restrict__ W,
    float* __restrict__ P) {
  __shared__ short Wl[64 * 136];
  __shared__ short Al[64 * 136];
  const int t = threadIdx.x;
  const int kc = blockIdx.x >> 2, nt = blockIdx.x & 3;
  const int w = t >> 6, lane = t & 63;
  const int l15 = lane & 15, lg = lane >> 4;
  const int wm = w >> 1, wn = w & 1;

  const int row = t >> 2, q = t & 3;
  const float* wsrc = W + (size_t)(nt * 64 + row) * KFC + kc * 2048 + q * 32;
  const unsigned short* asrc = A + (size_t)row * KFC + kc * 2048 + q * 32;

  f32x4 acc[2][2];
#pragma unroll
  for (int i = 0; i < 2; ++i)
#pragma unroll
    for (int j = 0; j < 2; ++j) acc[i][j] = (f32x4){0.f, 0.f, 0.f, 0.f};

  f32x4 wreg[8]; short8 areg[4];
#pragma unroll
  for (int i = 0; i < 8; ++i) wreg[i] = *(const f32x4*)(wsrc + i * 4);
#pragma unroll
  for (int i = 0; i < 4; ++i) areg[i] = *(const short8*)(asrc + i * 8);

  for (int it = 0; it < 16; ++it) {
    __syncthreads();
    {
      unsigned* wd = (unsigned*)&Wl[row * 136 + q * 32];
#pragma unroll
      for (int i = 0; i < 8; ++i) {
        f32x4 v = wreg[i];
        wd[i * 2 + 0] = (unsigned)f2bf(v[0]) | ((unsigned)f2bf(v[1]) << 16);
        wd[i * 2 + 1] = (unsigned)f2bf(v[2]) | ((unsigned)f2bf(v[3]) << 16);
      }
      short8* ad = (short8*)&Al[row * 136 + q * 32];
#pragma unroll
      for (int i = 0; i < 4; ++i) ad[i] = areg[i];
    }
    __syncthreads();
    if (it < 15) {
      const float* wp = wsrc + (it + 1) * 128;
      const unsigned short* ap = asrc + (it + 1) * 128;
#pragma unroll
      for (int i = 0; i < 8; ++i) wreg[i] = *(const f32x4*)(wp + i * 4);
#pragma unroll
      for (int i = 0; i < 4; ++i) areg[i] = *(const short8*)(ap + i * 8);
    }
#pragma unroll
    for (int ks = 0; ks < 4; ++ks) {
      short8 af0 = *(const short8*)&Al[(wm * 32 + l15) * 136 + ks * 32 + lg * 8];
      short8 af1 = *(const short8*)&Al[(wm * 32 + 16 + l15) * 136 + ks * 32 + lg * 8];
      short8 bf0 = *(const short8*)&Wl[(wn * 32 + l15) * 136 + ks * 32 + lg * 8];
      short8 bf1 = *(const short8*)&Wl[(wn * 32 + 16 + l15) * 136 + ks * 32 + lg * 8];
      acc[0][0] = __builtin_amdgcn_mfma_f32_16x16x32_bf16(af0, bf0, acc[0][0], 0, 0, 0);
      acc[0][1] = __builtin_amdgcn_mfma_f32_16x16x32_bf16(af0, bf1, acc[0][1], 0, 0, 0);
      acc[1][0] = __builtin_amdgcn_mfma_f32_16x16x32_bf16(af1, bf0, acc[1][0], 0, 0, 0);
      acc[1][1] = __builtin_amdgcn_mfma_f32_16x16x32_bf16(af1, bf1, acc[1][1], 0, 0, 0);
    }
  }

  float* dst = P + (size_t)kc * 16384;
#pragma unroll
  for (int mf = 0; mf < 2; ++mf)
#pragma unroll
    for (int nf = 0; nf < 2; ++nf)
#pragma unroll
      for (int j = 0; j < 4; ++j) {
        int brow = wm * 32 + mf * 16 + lg * 4 + j;
        int o = nt * 64 + wn * 32 + nf * 16 + l15;
        dst[brow * 256 + o] = acc[mf][nf][j];
      }
}

// fc1 partial reduce + bias + relu -> Y[64,256]
__global__ __launch_bounds__(256) void fc1_reduce_kernel(
    const float* __restrict__ P, const float* __restrict__ fb1,
    float* __restrict__ Y) {
  int idx = blockIdx.x * 256 + threadIdx.x;   // b*256 + o
  float s0 = 0, s1 = 0, s2 = 0, s3 = 0;
  for (int p = 0; p < 64; p += 4) {
    s0 += P[(size_t)(p + 0) * 16384 + idx];
    s1 += P[(size_t)(p + 1) * 16384 + idx];
    s2 += P[(size_t)(p + 2) * 16384 + idx];
    s3 += P[(size_t)(p + 3) * 16384 + idx];
  }
  float s = (s0 + s1) + (s2 + s3);
  Y[idx] = fmaxf(s + fb1[idx & 255], 0.f);
}

// fc2: out[64,1000] = Y[64,256] @ W2[1000,256]^T + b2
__global__ __launch_bounds__(256) void fc2_kernel(
    const float* __restrict__ Y, const float* __restrict__ W2,
    const float* __restrict__ b2, float* __restrict__ out) {
  int tid = blockIdx.x * 256 + threadIdx.x;
  if (tid >= 64 * NCLS) return;
  int b = tid / NCLS, n = tid - b * NCLS;
  const float4* yv = (const float4*)(Y + b * 256);
  const float4* wv = (const float4*)(W2 + n * 256);
  float acc = 0.f;
#pragma unroll 8
  for (int f = 0; f < 64; ++f) {
    float4 a = yv[f], w = wv[f];
    acc += a.x * w.x + a.y * w.y + a.z * w.z + a.w * w.w;
  }
  out[tid] = acc + b2[n];
}

// ---------------------------------------------------------------------------
extern "C" void kernel_launch(void* const* d_in, const int* in_sizes, int n_in,
                              void* d_out, int out_size, void* d_ws, size_t ws_size,
                              hipStream_t stream) {
  const float* x   = (const float*)d_in[0];
  const float* w1  = (const float*)d_in[1];
  const float* b1  = (const float*)d_in[2];
  const float* w2  = (const float*)d_in[3];
  const float* b2  = (const float*)d_in[4];
  const float* fw1 = (const float*)d_in[5];
  const float* fb1 = (const float*)d_in[6];
  const float* fw2 = (const float*)d_in[7];
  const float* fb2 = (const float*)d_in[8];
  float* out = (float*)d_out;

  float* ws0 = (float*)d_ws;                              // conv1 out fp32 [16777216]
  unsigned short* A16 = (unsigned short*)(ws0 + 16777216); // conv2 out bf16 [8388608]
  short* Bp = (short*)(A16 + 8388608);                     // reordered conv2 weights bf16 [73728]
  float* P  = (float*)(Bp + 73728);                        // fc1 partials [64*16384]
  float* Y  = P + 1048576;                                 // fc1 out [16384]

  prep_w2<<<288, 256, 0, stream>>>(w2, Bp);
  conv1_kernel<<<16384, 256, 0, stream>>>(x, w1, b1, ws0);
  conv2_mfma<<<1024, 256, 0, stream>>>(ws0, Bp, b2, (unsigned int*)A16);
  fc1_mfma<<<256, 256, 0, stream>>>(A16, fw1, P);
  fc1_reduce_kernel<<<64, 256, 0, stream>>>(P, fb1, Y);
  fc2_kernel<<<250, 256, 0, stream>>>(Y, fw2, fb2, out);
}

// Round 3
// 219.153 us; speedup vs baseline: 5.5201x; 2.4538x over previous
//
#include <hip/hip_runtime.h>

typedef __attribute__((ext_vector_type(8))) short short8;
typedef __attribute__((ext_vector_type(4))) float f32x4;

#define KFC   131072   // 128*32*32
#define NCLS  1000

__device__ __forceinline__ unsigned short f2bf(float f) {
  union { float f; unsigned u; } v; v.f = f;
  unsigned r = v.u + 0x7FFFu + ((v.u >> 16) & 1u);   // RNE
  return (unsigned short)(r >> 16);
}

// ---------------------------------------------------------------------------
// conv1: x[64,3,128,128] fp32 -> y[64,64,64,64] bf16 NHWC (b,ph,pw,c)
// block = (b, 32x32-conv tile); input window 3x34x34 staged once in LDS.
// thread = (c = t&63, quad = t>>6): 8x8 pooled region, LDS reads are wave-broadcast.
// ---------------------------------------------------------------------------
__global__ __launch_bounds__(256) void conv1_kernel(
    const float* __restrict__ x, const float* __restrict__ w1,
    const float* __restrict__ b1, unsigned short* __restrict__ y) {
  __shared__ float tile[3][34][36];
  const int t = threadIdx.x;
  const int blk = blockIdx.x;                 // b*16 + ty*4 + tx
  const int tx = blk & 3, ty = (blk >> 2) & 3, b = blk >> 4;
  const int ih0 = ty * 32 - 1, iw0 = tx * 32 - 1;

  // stage (coalesced along rows; pad cols 34..35 and out-of-image with 0)
  for (int i = t; i < 3 * 34 * 36; i += 256) {
    int ci = i / 1224, rem = i - ci * 1224;
    int r = rem / 36, s = rem - r * 36;
    int ih = ih0 + r, iw = iw0 + s;
    bool ok = (s < 34) && ((unsigned)ih < 128u) && ((unsigned)iw < 128u);
    tile[ci][r][s] = ok ? x[(b * 3 + ci) * 16384 + (ih << 7) + iw] : 0.f;
  }
  __syncthreads();

  const int c = t & 63, quad = t >> 6;
  const int qy = quad >> 1, qx = quad & 1;

  float wr[27];
#pragma unroll
  for (int k = 0; k < 27; ++k) wr[k] = w1[c * 27 + k];
  const float bias = b1[c];

#pragma unroll
  for (int pr = 0; pr < 8; ++pr) {
    float acc0[16], acc1[16];
#pragma unroll
    for (int i = 0; i < 16; ++i) { acc0[i] = 0.f; acc1[i] = 0.f; }

#pragma unroll
    for (int ci = 0; ci < 3; ++ci) {
      float rv[4][20];
#pragma unroll
      for (int r = 0; r < 4; ++r) {
        const float* rp = &tile[ci][qy * 16 + 2 * pr + r][qx * 16];
#pragma unroll
        for (int v4 = 0; v4 < 5; ++v4) {
          float4 v = *(const float4*)(rp + v4 * 4);
          rv[r][v4 * 4 + 0] = v.x; rv[r][v4 * 4 + 1] = v.y;
          rv[r][v4 * 4 + 2] = v.z; rv[r][v4 * 4 + 3] = v.w;
        }
      }
#pragma unroll
      for (int kh = 0; kh < 3; ++kh)
#pragma unroll
        for (int kw = 0; kw < 3; ++kw) {
          float wt = wr[ci * 9 + kh * 3 + kw];
#pragma unroll
          for (int w = 0; w < 16; ++w) {
            acc0[w] += rv[kh][w + kw] * wt;
            acc1[w] += rv[kh + 1][w + kw] * wt;
          }
        }
    }

    const int ph = ty * 16 + qy * 8 + pr;
    const int pwb = tx * 16 + qx * 8;
    unsigned short* dst = y + ((((size_t)b << 6) + ph) << 12) + ((size_t)pwb << 6) + c;
#pragma unroll
    for (int pw = 0; pw < 8; ++pw) {
      float m = fmaxf(fmaxf(acc0[2 * pw], acc0[2 * pw + 1]),
                      fmaxf(acc1[2 * pw], acc1[2 * pw + 1]));
      m = fmaxf(m + bias, 0.f);
      dst[(size_t)pw << 6] = f2bf(m);
    }
  }
}

// ---------------------------------------------------------------------------
// weight reorder for conv2: Bprep[((cg*9+pos)*128 + o)*32 + c] = bf16(w2[o][(cg*32+c)*9 + pos])
// ---------------------------------------------------------------------------
__global__ __launch_bounds__(256) void prep_w2(
    const float* __restrict__ w2, short* __restrict__ Bp) {
  int i = blockIdx.x * 256 + threadIdx.x;   // 73728 total
  int c = i & 31, o = (i >> 5) & 127, pp = i >> 12;
  int cg = pp / 9, pos = pp - cg * 9;
  Bp[i] = (short)f2bf(w2[o * 576 + (cg * 32 + c) * 9 + pos]);
}

// ---------------------------------------------------------------------------
// conv2 implicit-GEMM MFMA: y[64,64,64,64] bf16 NHWC -> A[64,131072] bf16 (flat [128,32,32])
// block: b x (4x4 grid of 16x16 conv tiles). 4 waves; wave = M 64 px x N 128 o.
// K = 2 chunks x (9 pos x 32 ch). LDS: [18*18 spatial][32ch + 8 pad] bf16.
// ---------------------------------------------------------------------------
__global__ __launch_bounds__(256) void conv2_mfma(
    const short* __restrict__ yin, const short* __restrict__ Bp,
    const float* __restrict__ b2, unsigned int* __restrict__ A32) {
  __shared__ short tile[324 * 40];
  const int t = threadIdx.x;
  const int blk = blockIdx.x;
  const int tx = blk & 3, ty = (blk >> 2) & 3, b = blk >> 4;
  const int w = t >> 6, lane = t & 63;
  const int l15 = lane & 15, lg = lane >> 4;

  f32x4 acc[4][8];
#pragma unroll
  for (int m = 0; m < 4; ++m)
#pragma unroll
    for (int n = 0; n < 8; ++n) acc[m][n] = (f32x4){0.f, 0.f, 0.f, 0.f};

  const int ih0 = ty * 16 - 1, iw0 = tx * 16 - 1;

#pragma unroll
  for (int cg = 0; cg < 2; ++cg) {
    __syncthreads();
    // stage 18x18 spatial x 32 channels from NHWC bf16: one short8 per (pixel, ch-octet)
    for (int i = t; i < 324 * 4; i += 256) {
      int p = i >> 2, q = i & 3;
      int sy = p / 18, sx = p - sy * 18;
      int ih = ih0 + sy, iw = iw0 + sx;
      short8 v = (short8){0, 0, 0, 0, 0, 0, 0, 0};
      if (((unsigned)ih < 64u) && ((unsigned)iw < 64u))
        v = *(const short8*)(yin + ((((size_t)b << 6) + ih) << 12) + ((size_t)iw << 6) + cg * 32 + q * 8);
      *(short8*)&tile[p * 40 + q * 8] = v;
    }
    __syncthreads();

    const int py0 = w * 4;
#pragma unroll
    for (int pos = 0; pos < 9; ++pos) {
      const int kh = pos / 3, kw = pos % 3;
      short8 af[4];
#pragma unroll
      for (int m = 0; m < 4; ++m) {
        int sy = py0 + m + kh, sx = l15 + kw;
        af[m] = *(const short8*)&tile[(sy * 18 + sx) * 40 + lg * 8];
      }
#pragma unroll
      for (int n = 0; n < 8; ++n) {
        const short8 bf = *(const short8*)(Bp + ((((cg * 9 + pos) << 7) + n * 16 + l15) << 5) + (lg << 3));
#pragma unroll
        for (int m = 0; m < 4; ++m)
          acc[m][n] = __builtin_amdgcn_mfma_f32_16x16x32_bf16(af[m], bf, acc[m][n], 0, 0, 0);
      }
    }
  }

  // epilogue: bias + relu + 2x2 pool, all in-lane; write packed bf16 pairs
  const size_t bbase = ((size_t)b << 16);   // u32 units
#pragma unroll
  for (int n = 0; n < 8; ++n) {
    const int o = n * 16 + l15;
    const float bias = b2[o];
#pragma unroll
    for (int mp = 0; mp < 2; ++mp) {
      const int prow = ty * 8 + w * 2 + mp;
      float v0 = fmaxf(fmaxf(acc[2 * mp][n][0], acc[2 * mp][n][1]),
                       fmaxf(acc[2 * mp + 1][n][0], acc[2 * mp + 1][n][1]));
      float v1 = fmaxf(fmaxf(acc[2 * mp][n][2], acc[2 * mp][n][3]),
                       fmaxf(acc[2 * mp + 1][n][2], acc[2 * mp + 1][n][3]));
      v0 = fmaxf(v0 + bias, 0.f);
      v1 = fmaxf(v1 + bias, 0.f);
      unsigned pk = (unsigned)f2bf(v0) | ((unsigned)f2bf(v1) << 16);
      A32[bbase + (size_t)o * 512 + prow * 16 + tx * 4 + lg] = pk;
    }
  }
}

// ---------------------------------------------------------------------------
// fc1 MFMA (BW-bound): C[64 b][256 o] partials over K-chunks of 2048.
// ---------------------------------------------------------------------------
__global__ __launch_bounds__(256) void fc1_mfma(
    const unsigned short* __restrict__ A, const float* __restrict__ W,
    float* __restrict__ P) {
  __shared__ short Wl[64 * 136];
  __shared__ short Al[64 * 136];
  const int t = threadIdx.x;
  const int kc = blockIdx.x >> 2, nt = blockIdx.x & 3;
  const int w = t >> 6, lane = t & 63;
  const int l15 = lane & 15, lg = lane >> 4;
  const int wm = w >> 1, wn = w & 1;

  const int row = t >> 2, q = t & 3;
  const float* wsrc = W + (size_t)(nt * 64 + row) * KFC + kc * 2048 + q * 32;
  const unsigned short* asrc = A + (size_t)row * KFC + kc * 2048 + q * 32;

  f32x4 acc[2][2];
#pragma unroll
  for (int i = 0; i < 2; ++i)
#pragma unroll
    for (int j = 0; j < 2; ++j) acc[i][j] = (f32x4){0.f, 0.f, 0.f, 0.f};

  f32x4 wreg[8]; short8 areg[4];
#pragma unroll
  for (int i = 0; i < 8; ++i) wreg[i] = *(const f32x4*)(wsrc + i * 4);
#pragma unroll
  for (int i = 0; i < 4; ++i) areg[i] = *(const short8*)(asrc + i * 8);

  for (int it = 0; it < 16; ++it) {
    __syncthreads();
    {
      unsigned* wd = (unsigned*)&Wl[row * 136 + q * 32];
#pragma unroll
      for (int i = 0; i < 8; ++i) {
        f32x4 v = wreg[i];
        wd[i * 2 + 0] = (unsigned)f2bf(v[0]) | ((unsigned)f2bf(v[1]) << 16);
        wd[i * 2 + 1] = (unsigned)f2bf(v[2]) | ((unsigned)f2bf(v[3]) << 16);
      }
      short8* ad = (short8*)&Al[row * 136 + q * 32];
#pragma unroll
      for (int i = 0; i < 4; ++i) ad[i] = areg[i];
    }
    __syncthreads();
    if (it < 15) {
      const float* wp = wsrc + (it + 1) * 128;
      const unsigned short* ap = asrc + (it + 1) * 128;
#pragma unroll
      for (int i = 0; i < 8; ++i) wreg[i] = *(const f32x4*)(wp + i * 4);
#pragma unroll
      for (int i = 0; i < 4; ++i) areg[i] = *(const short8*)(ap + i * 8);
    }
#pragma unroll
    for (int ks = 0; ks < 4; ++ks) {
      short8 af0 = *(const short8*)&Al[(wm * 32 + l15) * 136 + ks * 32 + lg * 8];
      short8 af1 = *(const short8*)&Al[(wm * 32 + 16 + l15) * 136 + ks * 32 + lg * 8];
      short8 bf0 = *(const short8*)&Wl[(wn * 32 + l15) * 136 + ks * 32 + lg * 8];
      short8 bf1 = *(const short8*)&Wl[(wn * 32 + 16 + l15) * 136 + ks * 32 + lg * 8];
      acc[0][0] = __builtin_amdgcn_mfma_f32_16x16x32_bf16(af0, bf0, acc[0][0], 0, 0, 0);
      acc[0][1] = __builtin_amdgcn_mfma_f32_16x16x32_bf16(af0, bf1, acc[0][1], 0, 0, 0);
      acc[1][0] = __builtin_amdgcn_mfma_f32_16x16x32_bf16(af1, bf0, acc[1][0], 0, 0, 0);
      acc[1][1] = __builtin_amdgcn_mfma_f32_16x16x32_bf16(af1, bf1, acc[1][1], 0, 0, 0);
    }
  }

  float* dst = P + (size_t)kc * 16384;
#pragma unroll
  for (int mf = 0; mf < 2; ++mf)
#pragma unroll
    for (int nf = 0; nf < 2; ++nf)
#pragma unroll
      for (int j = 0; j < 4; ++j) {
        int brow = wm * 32 + mf * 16 + lg * 4 + j;
        int o = nt * 64 + wn * 32 + nf * 16 + l15;
        dst[brow * 256 + o] = acc[mf][nf][j];
      }
}

// fc1 partial reduce + bias + relu -> Y[64,256]
__global__ __launch_bounds__(256) void fc1_reduce_kernel(
    const float* __restrict__ P, const float* __restrict__ fb1,
    float* __restrict__ Y) {
  int idx = blockIdx.x * 256 + threadIdx.x;   // b*256 + o
  float s0 = 0, s1 = 0, s2 = 0, s3 = 0;
  for (int p = 0; p < 64; p += 4) {
    s0 += P[(size_t)(p + 0) * 16384 + idx];
    s1 += P[(size_t)(p + 1) * 16384 + idx];
    s2 += P[(size_t)(p + 2) * 16384 + idx];
    s3 += P[(size_t)(p + 3) * 16384 + idx];
  }
  float s = (s0 + s1) + (s2 + s3);
  Y[idx] = fmaxf(s + fb1[idx & 255], 0.f);
}

// fc2: out[64,1000] = Y[64,256] @ W2[1000,256]^T + b2
__global__ __launch_bounds__(256) void fc2_kernel(
    const float* __restrict__ Y, const float* __restrict__ W2,
    const float* __restrict__ b2, float* __restrict__ out) {
  int tid = blockIdx.x * 256 + threadIdx.x;
  if (tid >= 64 * NCLS) return;
  int b = tid / NCLS, n = tid - b * NCLS;
  const float4* yv = (const float4*)(Y + b * 256);
  const float4* wv = (const float4*)(W2 + n * 256);
  float acc = 0.f;
#pragma unroll 8
  for (int f = 0; f < 64; ++f) {
    float4 a = yv[f], w = wv[f];
    acc += a.x * w.x + a.y * w.y + a.z * w.z + a.w * w.w;
  }
  out[tid] = acc + b2[n];
}

// ---------------------------------------------------------------------------
extern "C" void kernel_launch(void* const* d_in, const int* in_sizes, int n_in,
                              void* d_out, int out_size, void* d_ws, size_t ws_size,
                              hipStream_t stream) {
  const float* x   = (const float*)d_in[0];
  const float* w1  = (const float*)d_in[1];
  const float* b1  = (const float*)d_in[2];
  const float* w2  = (const float*)d_in[3];
  const float* b2  = (const float*)d_in[4];
  const float* fw1 = (const float*)d_in[5];
  const float* fb1 = (const float*)d_in[6];
  const float* fw2 = (const float*)d_in[7];
  const float* fb2 = (const float*)d_in[8];
  float* out = (float*)d_out;

  unsigned short* Y1 = (unsigned short*)d_ws;              // conv1 out bf16 NHWC [16777216]
  unsigned short* A16 = Y1 + 16777216;                     // conv2 out bf16 [8388608]
  short* Bp = (short*)(A16 + 8388608);                     // conv2 weights bf16 [73728]
  float* P  = (float*)(Bp + 73728);                        // fc1 partials [64*16384]
  float* Yf = P + 1048576;                                 // fc1 out [16384]

  prep_w2<<<288, 256, 0, stream>>>(w2, Bp);
  conv1_kernel<<<1024, 256, 0, stream>>>(x, w1, b1, Y1);
  conv2_mfma<<<1024, 256, 0, stream>>>((const short*)Y1, Bp, b2, (unsigned int*)A16);
  fc1_mfma<<<256, 256, 0, stream>>>(A16, fw1, P);
  fc1_reduce_kernel<<<64, 256, 0, stream>>>(P, fb1, Yf);
  fc2_kernel<<<250, 256, 0, stream>>>(Yf, fw2, fb2, out);
}